// Round 8
// baseline (84.457 us; speedup 1.0000x reference)
//
#include <hip/hip_runtime.h>

typedef __attribute__((ext_vector_type(8))) short short8;
typedef __attribute__((ext_vector_type(4))) float f32x4;

// ---------------- ws layout (bytes) ----------------
// rcp  : float [8][512]                        @ 0         (16384)
// wpre : bf16  [c=8][t=9][kb=8][co=512][8]     @ 16384     (4718592)
// xm   : bf16  [b=8][g=64][hp=34][col=34][8]   @ 4734976   (9469952)  (hp=0 / hp=33 are zero rows)
#define RCP_OFF   0
#define WPRE_OFF  16384
#define XM_OFF    4734976

__device__ __forceinline__ unsigned short f2bf(float f) {
  unsigned int u = __float_as_uint(f);
  u += 0x7FFFu + ((u >> 16) & 1u);       // round-to-nearest-even
  return (unsigned short)(u >> 16);
}

__device__ __forceinline__ void gload_lds16(const void* g, void* l) {
  __builtin_amdgcn_global_load_lds(
      (__attribute__((address_space(1))) void*)g,
      (__attribute__((address_space(3))) void*)l, 16, 0, 0);
}

// ---- fused prep: xm (0-511) | wpre (512-639) | xs (640-767) | zero-out (768-1023) ----
__global__ __launch_bounds__(256) void prep_kernel(
    const float* __restrict__ x, const float* __restrict__ ys,
    const float* __restrict__ w,
    unsigned short* __restrict__ xm, unsigned short* __restrict__ wpre,
    float* __restrict__ rcp, float* __restrict__ out) {
  int bid = blockIdx.x;
  int tid = threadIdx.x;

  if (bid < 512) {
    // ---- xm: modulated x -> bf16, channel-grouped, padded h & w ----
    int half = bid & 1;
    int h = (bid >> 1) & 31;
    int b = bid >> 6;
    __shared__ float tile[256][33];
    int ci0 = half * 256;
#pragma unroll
    for (int r = 0; r < 32; ++r) {
      int ci = r * 8 + (tid >> 5);
      int wcol = tid & 31;
      float v = x[(((size_t)b * 512 + ci0 + ci) * 32 + h) * 32 + wcol];
      tile[ci][wcol] = v * ys[b * 512 + ci0 + ci];
    }
    __syncthreads();
    int g0 = half * 32;
    for (int r = 0; r < 5; ++r) {
      int idx = r * 256 + tid;                     // [gl(32)][col(34)]
      if (idx < 1088) {
        int gl = idx / 34;
        int col = idx - gl * 34;
        short8 v = {0,0,0,0,0,0,0,0};
        if (col != 0 && col != 33) {
          int wcol = col - 1;
#pragma unroll
          for (int j = 0; j < 8; ++j)
            v[j] = (short)f2bf(tile[gl * 8 + j][wcol]);
        }
        size_t off = ((((size_t)b * 64 + g0 + gl) * 34 + (h + 1)) * 34 + col) * 8;
        *reinterpret_cast<short8*>(xm + off) = v;
      }
    }
    if (h == 0 || h == 31) {
      int hp = (h == 0) ? 0 : 33;
      for (int r = 0; r < 5; ++r) {
        int idx = r * 256 + tid;
        if (idx < 1088) {
          int gl = idx / 34;
          int col = idx - gl * 34;
          short8 z = {0,0,0,0,0,0,0,0};
          size_t off = ((((size_t)b * 64 + g0 + gl) * 34 + hp) * 34 + col) * 8;
          *reinterpret_cast<short8*>(xm + off) = z;
        }
      }
    }
  } else if (bid < 640) {
    // ---- wpre: scaled weight -> bf16 fragment layout ----
    int pid = bid - 512;             // [c(8)][kb(8)][coh(2)]
    int coh = pid & 1;
    int kb = (pid >> 1) & 7;
    int c = pid >> 4;
    int co = coh * 256 + tid;
    int ci0 = c * 64 + kb * 8;
    const float* wp = w + (size_t)co * 4608 + (size_t)ci0 * 9;   // 72 contiguous floats
    float v[72];
    const f32x4* wp4 = reinterpret_cast<const f32x4*>(wp);
#pragma unroll
    for (int i = 0; i < 18; ++i) {
      f32x4 q = wp4[i];
      v[i * 4 + 0] = q[0]; v[i * 4 + 1] = q[1]; v[i * 4 + 2] = q[2]; v[i * 4 + 3] = q[3];
    }
    const float scale = 1.4731391274719738e-02f;   // (512*9)^-0.5
#pragma unroll
    for (int t = 0; t < 9; ++t) {
      short8 s;
#pragma unroll
      for (int j = 0; j < 8; ++j) s[j] = (short)f2bf(scale * v[j * 9 + t]);
      *reinterpret_cast<short8*>(wpre + ((((size_t)c * 9 + t) * 8 + kb) * 512 + co) * 8) = s;
    }
  } else if (bid < 768) {
    // ---- xs: demod rcp[b][o], one wave per o ----
    int pid = bid - 640;
    int wv = tid >> 6;
    int lane = tid & 63;
    int o = pid * 4 + wv;
    const float* wp = w + (size_t)o * 4608 + (size_t)lane * 72;  // 8 ci x 9 taps
    const float scale2 = 1.0f / 4608.0f;
    float w2[8];
#pragma unroll
    for (int j = 0; j < 8; ++j) {
      float s = 0.f;
#pragma unroll
      for (int k = 0; k < 9; ++k) { float vv = wp[j * 9 + k]; s += vv * vv; }
      w2[j] = s * scale2;
    }
#pragma unroll
    for (int b = 0; b < 8; ++b) {
      float p = 0.f;
#pragma unroll
      for (int j = 0; j < 8; ++j) {
        float y = ys[b * 512 + lane * 8 + j];
        p += y * y * w2[j];
      }
#pragma unroll
      for (int off = 32; off > 0; off >>= 1) p += __shfl_down(p, off);
      if (lane == 0) rcp[b * 512 + o] = 1.0f / sqrtf(p + 1e-8f);
    }
  } else {
    // ---- zero-fill out (4.2M floats = 1M float4) for the atomic K-split ----
    int pid = bid - 768;             // 256 blocks x 256 thr x 16 float4
    f32x4* o4 = reinterpret_cast<f32x4*>(out);
    f32x4 z = {0.f, 0.f, 0.f, 0.f};
    int base = pid * 256 + tid;
#pragma unroll
    for (int i = 0; i < 16; ++i)
      o4[(size_t)i * 65536 + base] = z;
  }
}

// ---------------- main: implicit-GEMM direct conv, block-level K-split ----------------
// grid 512 = [sp(64)][cog(4)][kp(2)], block 512 thr = 8 waves (wc,wr spatial/co, kq
// K-quarter within chunk). kp = K-half at BLOCK level: each block does 4 ci-chunks
// (36 taps), so 2 independent blocks co-reside per CU (16 waves, 4/SIMD) — the
// m114 implicit overlap that the single-block m97-structure (R4-R6, pinned at
// ~850 TF) was missing. Per-CU A/xm traffic unchanged vs R6: XCD = kp+2*cog is
// fixed per XCD, so co-resident blocks share the same wpre working set.
// Partials combined via 2 fp32 atomicAdds per output (commutative => bit-
// deterministic); out is zero-filled by prep. bias added by kp==0 only.
__global__ __launch_bounds__(512, 4) void conv_main(
    const unsigned short* __restrict__ wpre,
    const unsigned short* __restrict__ xm,
    const float* __restrict__ rcp,
    const float* __restrict__ bias,
    float* __restrict__ out)
{
  __shared__ __align__(16) char smem[52224];

  int bid = blockIdx.x;
  int kp = bid & 1;                 // block-level K-half (chunks kp*4 .. kp*4+3)
  int cog = (bid >> 1) & 3;
  int sp = bid >> 3;                // 0..63
  int b = sp >> 3;
  int hg = sp & 7;
  int tid = threadIdx.x;
  int lane = tid & 63;
  int wv = tid >> 6;                // 0..7
  int wc = wv & 1;
  int wr = (wv >> 1) & 1;
  int kq = wv >> 2;                 // K-quarter (within-chunk kb split)
  int l15 = lane & 15, l4 = lane >> 4;

  f32x4 acc[4][4];
#pragma unroll
  for (int i = 0; i < 4; ++i)
#pragma unroll
    for (int jj = 0; jj < 4; ++jj) { f32x4 z = {0.f,0.f,0.f,0.f}; acc[i][jj] = z; }

  const unsigned short* xmb = xm + (size_t)b * (64 * 34 * 34 * 8);
  // A-frag base: element (kb = kq*4 + l4, co = cog*128 + wr*64 + l15)
  const unsigned short* wbase =
      wpre + ((size_t)(kq * 4 + l4) * 512 + cog * 128 + wr * 64 + l15) * 8;
  // loop-invariant B-frag LDS base
  const int bbase = (kq * 4 + l4) * 3264 + wc * 2 * 544 + l15 * 16;

  auto stageX = [&](int cg, int buf) {       // cg = GLOBAL chunk id
    char* xb = smem + buf * 26112;
#pragma unroll
    for (int r = 0; r < 4; ++r) {
      int idx = r * 512 + tid;               // [kb(8)][rr(6)][col(34)] = 1632 chunks
      if (idx < 1632) {
        int kb = idx / 204;
        int rem = idx - kb * 204;
        int rr = rem / 34;
        int col = rem - rr * 34;
        const unsigned short* src =
            xmb + (((size_t)(cg * 8 + kb) * 34 + hg * 4 + rr) * 34 + col) * 8;
        gload_lds16(src, xb + idx * 16);
      }
    }
  };

  auto loadA = [&](int ctg, short8 (&a)[4]) {   // ctg = GLOBAL tap id
    const unsigned short* p = wbase + (size_t)ctg * 32768;
#pragma unroll
    for (int mi = 0; mi < 4; ++mi)
      a[mi] = *reinterpret_cast<const short8*>(p + mi * 128);
  };

  auto loadB = [&](const char* xb, int t, short8 (&f)[4]) {
    int kh = t / 3, kw = t % 3;              // compile-time (t unrolled)
#pragma unroll
    for (int nj = 0; nj < 4; ++nj) {
      int imm = ((nj >> 1) + kh) * 544 + (nj & 1) * 256 + kw * 16;
      f[nj] = *reinterpret_cast<const short8*>(xb + bbase + imm);
    }
  };

  short8 X[4], Y[4], Z[4];          // depth-2 A pipeline, roles rotate t%3 (9%3==0)
  const int tap0 = kp * 36;         // block's first global tap

  // prologue
  stageX(kp * 4, 0);
  loadA(tap0, X);
  loadA(tap0 + 1, Y);
  asm volatile("s_waitcnt vmcnt(8)" ::: "memory");   // stageX done; loadA may fly
  __builtin_amdgcn_s_barrier();
  asm volatile("" ::: "memory");

  for (int c = 0; c < 4; ++c) {     // local chunk; global cg = kp*4 + c
    const char* xb = smem + (c & 1) * 26112;
    if (c < 3) stageX(kp * 4 + c + 1, (c + 1) & 1);  // async; drains at chunk barrier
    short8 Bp[4], Bq[4];
    loadB(xb, 0, Bp);
#pragma unroll
    for (int t = 0; t < 9; ++t) {
      int lt = c * 9 + t;                    // local tap 0..35
      short8 (&curA)[4] = (t % 3 == 0) ? X : ((t % 3 == 1) ? Y : Z);   // static
      short8 (&nxtA)[4] = (t % 3 == 0) ? Z : ((t % 3 == 1) ? X : Y);   // (t+2)%3
      short8 (&curB)[4] = (t & 1) ? Bq : Bp;
      short8 (&nxtB)[4] = (t & 1) ? Bp : Bq;
      if (lt < 34) loadA(tap0 + lt + 2, nxtA);   // depth-2 A prefetch
      if (t < 8) loadB(xb, t + 1, nxtB);         // next-tap B prefetch (LDS)
#pragma unroll
      for (int nj = 0; nj < 4; ++nj)
#pragma unroll
        for (int mi = 0; mi < 4; ++mi)
          acc[mi][nj] = __builtin_amdgcn_mfma_f32_16x16x32_bf16(curA[mi], curB[nj], acc[mi][nj], 0, 0, 0);
    }
    if (c < 3) {
      // stageX(c+1) must be done; the 8 newest vmem (A prefetches) stay in flight.
      asm volatile("s_waitcnt vmcnt(8) lgkmcnt(0)" ::: "memory");
      __builtin_amdgcn_s_barrier();
      asm volatile("" ::: "memory");
    }
  }
  __syncthreads();                  // full drain before smem reuse

  // ---- within-block kq reduction (kq1 -> LDS -> kq0) ----
#pragma unroll
  for (int p = 0; p < 2; ++p) {
    if (kq == 1 && wr == p) {
#pragma unroll
      for (int mi = 0; mi < 4; ++mi)
#pragma unroll
        for (int nj = 0; nj < 4; ++nj)
          *reinterpret_cast<f32x4*>(smem + wc * 16384 + (mi * 4 + nj) * 1024 + lane * 16) = acc[mi][nj];
    }
    __syncthreads();
    if (kq == 0 && wr == p) {
#pragma unroll
      for (int mi = 0; mi < 4; ++mi)
#pragma unroll
        for (int nj = 0; nj < 4; ++nj) {
          f32x4 v = *reinterpret_cast<const f32x4*>(smem + wc * 16384 + (mi * 4 + nj) * 1024 + lane * 16);
          acc[mi][nj] = acc[mi][nj] + v;
        }
    }
    __syncthreads();
  }

  // ---- epilogue: demod (+bias for kp0), atomic accumulate into zeroed out ----
  if (kq == 0) {
    const float* rcpb = rcp + b * 512;
#pragma unroll
    for (int mi = 0; mi < 4; ++mi) {
      int ob = cog * 128 + wr * 64 + mi * 16 + l4 * 4;
      float rc[4], bi[4];
#pragma unroll
      for (int jj = 0; jj < 4; ++jj) {
        rc[jj] = rcpb[ob + jj];
        bi[jj] = kp ? 0.f : bias[ob + jj];
      }
#pragma unroll
      for (int nj = 0; nj < 4; ++nj) {
        int row4 = wc * 2 + (nj >> 1);
        int wcol = (nj & 1) * 16 + l15;
        int h = hg * 4 + row4;
#pragma unroll
        for (int jj = 0; jj < 4; ++jj)
          atomicAdd(&out[(((size_t)b * 512 + ob + jj) * 32 + h) * 32 + wcol],
                    acc[mi][nj][jj] * rc[jj] + bi[jj]);
      }
    }
  }
}

extern "C" void kernel_launch(void* const* d_in, const int* in_sizes, int n_in,
                              void* d_out, int out_size, void* d_ws, size_t ws_size,
                              hipStream_t stream) {
  const float* x    = (const float*)d_in[0];
  const float* ys   = (const float*)d_in[1];
  const float* w    = (const float*)d_in[2];
  const float* bias = (const float*)d_in[3];
  float* out = (float*)d_out;
  char* ws = (char*)d_ws;
  float* rcp = (float*)(ws + RCP_OFF);
  unsigned short* wpre = (unsigned short*)(ws + WPRE_OFF);
  unsigned short* xm   = (unsigned short*)(ws + XM_OFF);

  prep_kernel<<<1024, 256, 0, stream>>>(x, ys, w, xm, wpre, rcp, out);
  conv_main<<<512, 512, 0, stream>>>(wpre, xm, rcp, bias, out);
}

// Round 9
// 55.115 us; speedup vs baseline: 1.5324x; 1.5324x over previous
//
#include <hip/hip_runtime.h>

typedef __attribute__((ext_vector_type(8))) short short8;
typedef __attribute__((ext_vector_type(4))) float f32x4;

// ---------------- ws layout (bytes) ----------------
// rcp  : float [8][512]                        @ 0         (16384)
// wpre : bf16  [c=8][t=9][kb=8][co=512][8]     @ 16384     (4718592)
// xm   : bf16  [b=8][g=64][hp=34][col=34][8]   @ 4734976   (9469952)  (hp=0 / hp=33 are zero rows)
#define RCP_OFF   0
#define WPRE_OFF  16384
#define XM_OFF    4734976

__device__ __forceinline__ unsigned short f2bf(float f) {
  unsigned int u = __float_as_uint(f);
  u += 0x7FFFu + ((u >> 16) & 1u);       // round-to-nearest-even
  return (unsigned short)(u >> 16);
}

__device__ __forceinline__ void gload_lds16(const void* g, void* l) {
  __builtin_amdgcn_global_load_lds(
      (__attribute__((address_space(1))) void*)g,
      (__attribute__((address_space(3))) void*)l, 16, 0, 0);
}

// ---------------- fused prep: xm (blocks 0-511) | wpre (512-639) | xs (640-767) ----------------
__global__ __launch_bounds__(256) void prep_kernel(
    const float* __restrict__ x, const float* __restrict__ ys,
    const float* __restrict__ w,
    unsigned short* __restrict__ xm, unsigned short* __restrict__ wpre,
    float* __restrict__ rcp) {
  int bid = blockIdx.x;
  int tid = threadIdx.x;

  if (bid < 512) {
    // ---- xm: modulated x -> bf16, channel-grouped, padded h & w ----
    int half = bid & 1;
    int h = (bid >> 1) & 31;
    int b = bid >> 6;
    __shared__ float tile[256][33];
    int ci0 = half * 256;
#pragma unroll
    for (int r = 0; r < 32; ++r) {
      int ci = r * 8 + (tid >> 5);
      int wcol = tid & 31;
      float v = x[(((size_t)b * 512 + ci0 + ci) * 32 + h) * 32 + wcol];
      tile[ci][wcol] = v * ys[b * 512 + ci0 + ci];
    }
    __syncthreads();
    int g0 = half * 32;
    for (int r = 0; r < 5; ++r) {
      int idx = r * 256 + tid;                     // [gl(32)][col(34)]
      if (idx < 1088) {
        int gl = idx / 34;
        int col = idx - gl * 34;
        short8 v = {0,0,0,0,0,0,0,0};
        if (col != 0 && col != 33) {
          int wcol = col - 1;
#pragma unroll
          for (int j = 0; j < 8; ++j)
            v[j] = (short)f2bf(tile[gl * 8 + j][wcol]);
        }
        size_t off = ((((size_t)b * 64 + g0 + gl) * 34 + (h + 1)) * 34 + col) * 8;
        *reinterpret_cast<short8*>(xm + off) = v;
      }
    }
    if (h == 0 || h == 31) {
      int hp = (h == 0) ? 0 : 33;
      for (int r = 0; r < 5; ++r) {
        int idx = r * 256 + tid;
        if (idx < 1088) {
          int gl = idx / 34;
          int col = idx - gl * 34;
          short8 z = {0,0,0,0,0,0,0,0};
          size_t off = ((((size_t)b * 64 + g0 + gl) * 34 + hp) * 34 + col) * 8;
          *reinterpret_cast<short8*>(xm + off) = z;
        }
      }
    }
  } else if (bid < 640) {
    // ---- wpre: scaled weight -> bf16 fragment layout ----
    int pid = bid - 512;             // [c(8)][kb(8)][coh(2)]
    int coh = pid & 1;
    int kb = (pid >> 1) & 7;
    int c = pid >> 4;
    int co = coh * 256 + tid;
    int ci0 = c * 64 + kb * 8;
    const float* wp = w + (size_t)co * 4608 + (size_t)ci0 * 9;   // 72 contiguous floats
    float v[72];
    const f32x4* wp4 = reinterpret_cast<const f32x4*>(wp);
#pragma unroll
    for (int i = 0; i < 18; ++i) {
      f32x4 q = wp4[i];
      v[i * 4 + 0] = q[0]; v[i * 4 + 1] = q[1]; v[i * 4 + 2] = q[2]; v[i * 4 + 3] = q[3];
    }
    const float scale = 1.4731391274719738e-02f;   // (512*9)^-0.5
#pragma unroll
    for (int t = 0; t < 9; ++t) {
      short8 s;
#pragma unroll
      for (int j = 0; j < 8; ++j) s[j] = (short)f2bf(scale * v[j * 9 + t]);
      *reinterpret_cast<short8*>(wpre + ((((size_t)c * 9 + t) * 8 + kb) * 512 + co) * 8) = s;
    }
  } else {
    // ---- xs: demod rcp[b][o], one wave per o ----
    int pid = bid - 640;
    int wv = tid >> 6;
    int lane = tid & 63;
    int o = pid * 4 + wv;
    const float* wp = w + (size_t)o * 4608 + (size_t)lane * 72;  // 8 ci x 9 taps
    const float scale2 = 1.0f / 4608.0f;
    float w2[8];
#pragma unroll
    for (int j = 0; j < 8; ++j) {
      float s = 0.f;
#pragma unroll
      for (int k = 0; k < 9; ++k) { float vv = wp[j * 9 + k]; s += vv * vv; }
      w2[j] = s * scale2;
    }
#pragma unroll
    for (int b = 0; b < 8; ++b) {
      float p = 0.f;
#pragma unroll
      for (int j = 0; j < 8; ++j) {
        float y = ys[b * 512 + lane * 8 + j];
        p += y * y * w2[j];
      }
#pragma unroll
      for (int off = 32; off > 0; off >>= 1) p += __shfl_down(p, off);
      if (lane == 0) rcp[b * 512 + o] = 1.0f / sqrtf(p + 1e-8f);
    }
  }
}

// ---------------- main: implicit-GEMM direct conv, tap-phase schedule ----------------
// grid 256 (XCD-pinned cog), block 512 = 8 waves (wc,wr 2x2 spatial, kp K-split).
// R8 falsified occupancy-starvation (2 blocks/CU: zero K-loop gain). The stall
// is schedule quality: m201 hits 62% MfmaUtil at the SAME 2 waves/SIMD via
// per-phase {barrier; lgkmcnt(0); sched_barrier; setprio; MFMA-cluster}. Port:
// each tap is a phase. Per tap: issue A-prefetch (global, in flight across
// phases, T4) -> issue this tap's 4 ds_read B-frags -> s_barrier (align, NO
// drain) -> lgkmcnt(0) -> sched_barrier(0) (rule #18) -> setprio(1) -> 16 MFMA
// -> setprio(0). Counted vmcnt(8) only at chunk boundaries (stageX drain).
__global__ __launch_bounds__(512, 1) void conv_main(
    const unsigned short* __restrict__ wpre,
    const unsigned short* __restrict__ xm,
    const float* __restrict__ rcp,
    const float* __restrict__ bias,
    float* __restrict__ out)
{
  __shared__ __align__(16) char smem[52224];

  int bid = blockIdx.x;
  int xcd = bid & 7;
  int j0 = bid >> 3;                // 0..31 within XCD
  int cog = xcd >> 1;               // 2 XCDs per cog
  int sp = (xcd & 1) * 32 + j0;
  int b = sp >> 3;
  int hg = sp & 7;
  int tid = threadIdx.x;
  int lane = tid & 63;
  int wv = tid >> 6;                // 0..7
  int wc = wv & 1;
  int wr = (wv >> 1) & 1;
  int kp = wv >> 2;                 // K-split half
  int l15 = lane & 15, l4 = lane >> 4;

  f32x4 acc[4][4];
#pragma unroll
  for (int i = 0; i < 4; ++i)
#pragma unroll
    for (int jj = 0; jj < 4; ++jj) { f32x4 z = {0.f,0.f,0.f,0.f}; acc[i][jj] = z; }

  const unsigned short* xmb = xm + (size_t)b * (64 * 34 * 34 * 8);
  const unsigned short* wbase =
      wpre + ((size_t)(kp * 4 + l4) * 512 + cog * 128 + wr * 64 + l15) * 8;
  const int bbase = (kp * 4 + l4) * 3264 + wc * 2 * 544 + l15 * 16;

  auto stageX = [&](int c, int buf) {
    char* xb = smem + buf * 26112;
#pragma unroll
    for (int r = 0; r < 4; ++r) {
      int idx = r * 512 + tid;                 // [kb(8)][rr(6)][col(34)] = 1632 chunks
      if (idx < 1632) {
        int kb = idx / 204;
        int rem = idx - kb * 204;
        int rr = rem / 34;
        int col = rem - rr * 34;
        const unsigned short* src =
            xmb + (((size_t)(c * 8 + kb) * 34 + hg * 4 + rr) * 34 + col) * 8;
        gload_lds16(src, xb + idx * 16);
      }
    }
  };

  auto loadA = [&](int ct, short8 (&a)[4]) {
    const unsigned short* p = wbase + (size_t)ct * 32768;
#pragma unroll
    for (int mi = 0; mi < 4; ++mi)
      a[mi] = *reinterpret_cast<const short8*>(p + mi * 128);
  };

  auto loadB = [&](const char* xb, int t, short8 (&f)[4]) {
    int kh = t / 3, kw = t % 3;              // compile-time (t unrolled)
#pragma unroll
    for (int nj = 0; nj < 4; ++nj) {
      int imm = ((nj >> 1) + kh) * 544 + (nj & 1) * 256 + kw * 16;
      f[nj] = *reinterpret_cast<const short8*>(xb + bbase + imm);
    }
  };

  short8 X[4], Y[4], Z[4];          // depth-2 A pipeline, roles rotate t%3 (9%3==0)

  // prologue
  stageX(0, 0);
  loadA(0, X);
  loadA(1, Y);
  asm volatile("s_waitcnt vmcnt(8)" ::: "memory");   // stageX(0) done; A-loads fly
  __builtin_amdgcn_s_barrier();
  asm volatile("" ::: "memory");

  for (int c = 0; c < 8; ++c) {
    const char* xb = smem + (c & 1) * 26112;
    if (c < 7) stageX(c + 1, (c + 1) & 1);   // async; drains at chunk-end barrier
#pragma unroll
    for (int t = 0; t < 9; ++t) {
      int ct = c * 9 + t;
      short8 (&curA)[4] = (t % 3 == 0) ? X : ((t % 3 == 1) ? Y : Z);   // static
      short8 (&nxtA)[4] = (t % 3 == 0) ? Z : ((t % 3 == 1) ? X : Y);   // (t+2)%3
      if (ct < 70) loadA(ct + 2, nxtA);      // depth-2 global prefetch (stays in flight)
      short8 Bf[4];
      loadB(xb, t, Bf);                      // this tap's 4 ds_read_b128
      __builtin_amdgcn_s_barrier();          // phase-align the 8 waves (no drain)
      asm volatile("s_waitcnt lgkmcnt(0)" ::: "memory");
      __builtin_amdgcn_sched_barrier(0);     // rule #18: MFMA must not hoist past wait
      __builtin_amdgcn_s_setprio(1);
#pragma unroll
      for (int nj = 0; nj < 4; ++nj)
#pragma unroll
        for (int mi = 0; mi < 4; ++mi)
          acc[mi][nj] = __builtin_amdgcn_mfma_f32_16x16x32_bf16(curA[mi], Bf[nj], acc[mi][nj], 0, 0, 0);
      __builtin_amdgcn_s_setprio(0);
    }
    if (c < 7) {
      // counted drain: stageX(c+1) done; 8 newest vmem (A prefetches) in flight.
      asm volatile("s_waitcnt vmcnt(8) lgkmcnt(0)" ::: "memory");
      __builtin_amdgcn_s_barrier();
      asm volatile("" ::: "memory");
    }
  }
  __syncthreads();                  // full drain before smem reuse

  // ---- K-split reduction (kp1 -> LDS -> kp0) ----
#pragma unroll
  for (int p = 0; p < 2; ++p) {
    if (kp == 1 && wr == p) {
#pragma unroll
      for (int mi = 0; mi < 4; ++mi)
#pragma unroll
        for (int nj = 0; nj < 4; ++nj)
          *reinterpret_cast<f32x4*>(smem + wc * 16384 + (mi * 4 + nj) * 1024 + lane * 16) = acc[mi][nj];
    }
    __syncthreads();
    if (kp == 0 && wr == p) {
#pragma unroll
      for (int mi = 0; mi < 4; ++mi)
#pragma unroll
        for (int nj = 0; nj < 4; ++nj) {
          f32x4 v = *reinterpret_cast<const f32x4*>(smem + wc * 16384 + (mi * 4 + nj) * 1024 + lane * 16);
          acc[mi][nj] = acc[mi][nj] + v;
        }
    }
    __syncthreads();
  }

  // ---- epilogue: demod + bias, fp32 NCHW store ----
  if (kp == 0) {
    const float* rcpb = rcp + b * 512;
#pragma unroll
    for (int mi = 0; mi < 4; ++mi) {
      int ob = cog * 128 + wr * 64 + mi * 16 + l4 * 4;
      float rc[4], bi[4];
#pragma unroll
      for (int jj = 0; jj < 4; ++jj) { rc[jj] = rcpb[ob + jj]; bi[jj] = bias[ob + jj]; }
#pragma unroll
      for (int nj = 0; nj < 4; ++nj) {
        int row4 = wc * 2 + (nj >> 1);
        int wcol = (nj & 1) * 16 + l15;
        int h = hg * 4 + row4;
#pragma unroll
        for (int jj = 0; jj < 4; ++jj)
          out[(((size_t)b * 512 + ob + jj) * 32 + h) * 32 + wcol] = acc[mi][nj][jj] * rc[jj] + bi[jj];
      }
    }
  }
}

extern "C" void kernel_launch(void* const* d_in, const int* in_sizes, int n_in,
                              void* d_out, int out_size, void* d_ws, size_t ws_size,
                              hipStream_t stream) {
  const float* x    = (const float*)d_in[0];
  const float* ys   = (const float*)d_in[1];
  const float* w    = (const float*)d_in[2];
  const float* bias = (const float*)d_in[3];
  float* out = (float*)d_out;
  char* ws = (char*)d_ws;
  float* rcp = (float*)(ws + RCP_OFF);
  unsigned short* wpre = (unsigned short*)(ws + WPRE_OFF);
  unsigned short* xm   = (unsigned short*)(ws + XM_OFF);

  prep_kernel<<<768, 256, 0, stream>>>(x, ys, w, xm, wpre, rcp);
  conv_main<<<256, 512, 0, stream>>>(wpre, xm, rcp, bias, out);
}

// Round 10
// 54.838 us; speedup vs baseline: 1.5401x; 1.0050x over previous
//
#include <hip/hip_runtime.h>

typedef __attribute__((ext_vector_type(8))) short short8;
typedef __attribute__((ext_vector_type(4))) float f32x4;

// ---------------- ws layout (bytes) ----------------
// rcp  : float [8][512]                        @ 0         (16384)
// wpre : bf16  [c=8][t=9][kb=8][co=512][8]     @ 16384     (4718592)
// xm   : bf16  [b=8][g=64][hp=34][col=34][8]   @ 4734976   (9469952)  (hp=0 / hp=33 are zero rows)
#define RCP_OFF   0
#define WPRE_OFF  16384
#define XM_OFF    4734976

__device__ __forceinline__ unsigned short f2bf(float f) {
  unsigned int u = __float_as_uint(f);
  u += 0x7FFFu + ((u >> 16) & 1u);       // round-to-nearest-even
  return (unsigned short)(u >> 16);
}

__device__ __forceinline__ void gload_lds16(const void* g, void* l) {
  __builtin_amdgcn_global_load_lds(
      (__attribute__((address_space(1))) void*)g,
      (__attribute__((address_space(3))) void*)l, 16, 0, 0);
}

// ---------------- fused prep: xm (blocks 0-511) | wpre (512-639) | xs (640-767) ----------------
__global__ __launch_bounds__(256) void prep_kernel(
    const float* __restrict__ x, const float* __restrict__ ys,
    const float* __restrict__ w,
    unsigned short* __restrict__ xm, unsigned short* __restrict__ wpre,
    float* __restrict__ rcp) {
  int bid = blockIdx.x;
  int tid = threadIdx.x;

  if (bid < 512) {
    // ---- xm: modulated x -> bf16, channel-grouped, padded h & w ----
    int half = bid & 1;
    int h = (bid >> 1) & 31;
    int b = bid >> 6;
    __shared__ float tile[256][33];
    int ci0 = half * 256;
#pragma unroll
    for (int r = 0; r < 32; ++r) {
      int ci = r * 8 + (tid >> 5);
      int wcol = tid & 31;
      float v = x[(((size_t)b * 512 + ci0 + ci) * 32 + h) * 32 + wcol];
      tile[ci][wcol] = v * ys[b * 512 + ci0 + ci];
    }
    __syncthreads();
    int g0 = half * 32;
    for (int r = 0; r < 5; ++r) {
      int idx = r * 256 + tid;                     // [gl(32)][col(34)]
      if (idx < 1088) {
        int gl = idx / 34;
        int col = idx - gl * 34;
        short8 v = {0,0,0,0,0,0,0,0};
        if (col != 0 && col != 33) {
          int wcol = col - 1;
#pragma unroll
          for (int j = 0; j < 8; ++j)
            v[j] = (short)f2bf(tile[gl * 8 + j][wcol]);
        }
        size_t off = ((((size_t)b * 64 + g0 + gl) * 34 + (h + 1)) * 34 + col) * 8;
        *reinterpret_cast<short8*>(xm + off) = v;
      }
    }
    if (h == 0 || h == 31) {
      int hp = (h == 0) ? 0 : 33;
      for (int r = 0; r < 5; ++r) {
        int idx = r * 256 + tid;
        if (idx < 1088) {
          int gl = idx / 34;
          int col = idx - gl * 34;
          short8 z = {0,0,0,0,0,0,0,0};
          size_t off = ((((size_t)b * 64 + g0 + gl) * 34 + hp) * 34 + col) * 8;
          *reinterpret_cast<short8*>(xm + off) = z;
        }
      }
    }
  } else if (bid < 640) {
    // ---- wpre: scaled weight -> bf16 fragment layout ----
    int pid = bid - 512;             // [c(8)][kb(8)][coh(2)]
    int coh = pid & 1;
    int kb = (pid >> 1) & 7;
    int c = pid >> 4;
    int co = coh * 256 + tid;
    int ci0 = c * 64 + kb * 8;
    const float* wp = w + (size_t)co * 4608 + (size_t)ci0 * 9;   // 72 contiguous floats
    float v[72];
    const f32x4* wp4 = reinterpret_cast<const f32x4*>(wp);
#pragma unroll
    for (int i = 0; i < 18; ++i) {
      f32x4 q = wp4[i];
      v[i * 4 + 0] = q[0]; v[i * 4 + 1] = q[1]; v[i * 4 + 2] = q[2]; v[i * 4 + 3] = q[3];
    }
    const float scale = 1.4731391274719738e-02f;   // (512*9)^-0.5
#pragma unroll
    for (int t = 0; t < 9; ++t) {
      short8 s;
#pragma unroll
      for (int j = 0; j < 8; ++j) s[j] = (short)f2bf(scale * v[j * 9 + t]);
      *reinterpret_cast<short8*>(wpre + ((((size_t)c * 9 + t) * 8 + kb) * 512 + co) * 8) = s;
    }
  } else {
    // ---- xs: demod rcp[b][o], one wave per o ----
    int pid = bid - 640;
    int wv = tid >> 6;
    int lane = tid & 63;
    int o = pid * 4 + wv;
    const float* wp = w + (size_t)o * 4608 + (size_t)lane * 72;  // 8 ci x 9 taps
    const float scale2 = 1.0f / 4608.0f;
    float w2[8];
#pragma unroll
    for (int j = 0; j < 8; ++j) {
      float s = 0.f;
#pragma unroll
      for (int k = 0; k < 9; ++k) { float vv = wp[j * 9 + k]; s += vv * vv; }
      w2[j] = s * scale2;
    }
#pragma unroll
    for (int b = 0; b < 8; ++b) {
      float p = 0.f;
#pragma unroll
      for (int j = 0; j < 8; ++j) {
        float y = ys[b * 512 + lane * 8 + j];
        p += y * y * w2[j];
      }
#pragma unroll
      for (int off = 32; off > 0; off >>= 1) p += __shfl_down(p, off);
      if (lane == 0) rcp[b * 512 + o] = 1.0f / sqrtf(p + 1e-8f);
    }
  }
}

// ---------------- main: implicit-GEMM direct conv, tap-phase schedule ----------------
// grid 256 (XCD-pinned cog), block 512 = 8 waves (wc,wr 2x2 spatial, kp K-split).
// R9 (phases+setprio) was the first schedule win. R10 adds the missing combo
// piece: cross-tap B register double-buffer — B(t+1)'s 4 ds_read_b128 are
// issued right after tap t's lgkm wait, so their ~120cyc latency hides under
// the 16-MFMA cluster; each tap's lgkmcnt(0) is then ~free (one exposed B
// latency per CHUNK instead of per tap). R6 showed B-dbuf alone = null; the
// value is only in combination with the phase alignment (T3->T4->T5 graph).
// Counted vmcnt(8) only at chunk boundaries (stageX drain; 8 newest = A pf).
__global__ __launch_bounds__(512, 1) void conv_main(
    const unsigned short* __restrict__ wpre,
    const unsigned short* __restrict__ xm,
    const float* __restrict__ rcp,
    const float* __restrict__ bias,
    float* __restrict__ out)
{
  __shared__ __align__(16) char smem[52224];

  int bid = blockIdx.x;
  int xcd = bid & 7;
  int j0 = bid >> 3;                // 0..31 within XCD
  int cog = xcd >> 1;               // 2 XCDs per cog
  int sp = (xcd & 1) * 32 + j0;
  int b = sp >> 3;
  int hg = sp & 7;
  int tid = threadIdx.x;
  int lane = tid & 63;
  int wv = tid >> 6;                // 0..7
  int wc = wv & 1;
  int wr = (wv >> 1) & 1;
  int kp = wv >> 2;                 // K-split half
  int l15 = lane & 15, l4 = lane >> 4;

  f32x4 acc[4][4];
#pragma unroll
  for (int i = 0; i < 4; ++i)
#pragma unroll
    for (int jj = 0; jj < 4; ++jj) { f32x4 z = {0.f,0.f,0.f,0.f}; acc[i][jj] = z; }

  const unsigned short* xmb = xm + (size_t)b * (64 * 34 * 34 * 8);
  const unsigned short* wbase =
      wpre + ((size_t)(kp * 4 + l4) * 512 + cog * 128 + wr * 64 + l15) * 8;
  const int bbase = (kp * 4 + l4) * 3264 + wc * 2 * 544 + l15 * 16;

  auto stageX = [&](int c, int buf) {
    char* xb = smem + buf * 26112;
#pragma unroll
    for (int r = 0; r < 4; ++r) {
      int idx = r * 512 + tid;                 // [kb(8)][rr(6)][col(34)] = 1632 chunks
      if (idx < 1632) {
        int kb = idx / 204;
        int rem = idx - kb * 204;
        int rr = rem / 34;
        int col = rem - rr * 34;
        const unsigned short* src =
            xmb + (((size_t)(c * 8 + kb) * 34 + hg * 4 + rr) * 34 + col) * 8;
        gload_lds16(src, xb + idx * 16);
      }
    }
  };

  auto loadA = [&](int ct, short8 (&a)[4]) {
    const unsigned short* p = wbase + (size_t)ct * 32768;
#pragma unroll
    for (int mi = 0; mi < 4; ++mi)
      a[mi] = *reinterpret_cast<const short8*>(p + mi * 128);
  };

  auto loadB = [&](const char* xb, int t, short8 (&f)[4]) {
    int kh = t / 3, kw = t % 3;              // compile-time (t unrolled)
#pragma unroll
    for (int nj = 0; nj < 4; ++nj) {
      int imm = ((nj >> 1) + kh) * 544 + (nj & 1) * 256 + kw * 16;
      f[nj] = *reinterpret_cast<const short8*>(xb + bbase + imm);
    }
  };

  short8 X[4], Y[4], Z[4];          // depth-2 A pipeline, roles rotate t%3 (9%3==0)

  // prologue
  stageX(0, 0);
  loadA(0, X);
  loadA(1, Y);
  asm volatile("s_waitcnt vmcnt(8)" ::: "memory");   // stageX(0) done; A-loads fly
  __builtin_amdgcn_s_barrier();
  asm volatile("" ::: "memory");

  for (int c = 0; c < 8; ++c) {
    const char* xb = smem + (c & 1) * 26112;
    if (c < 7) stageX(c + 1, (c + 1) & 1);   // async; drains at chunk-end barrier
    short8 Bp[4], Bq[4];                     // cross-tap B reg dbuf (chunk-local)
    loadB(xb, 0, Bp);                        // one exposed B latency per chunk
#pragma unroll
    for (int t = 0; t < 9; ++t) {
      int ct = c * 9 + t;
      short8 (&curA)[4] = (t % 3 == 0) ? X : ((t % 3 == 1) ? Y : Z);   // static
      short8 (&nxtA)[4] = (t % 3 == 0) ? Z : ((t % 3 == 1) ? X : Y);   // (t+2)%3
      short8 (&curB)[4] = (t & 1) ? Bq : Bp;
      short8 (&nxtB)[4] = (t & 1) ? Bp : Bq;
      if (ct < 70) loadA(ct + 2, nxtA);      // depth-2 global prefetch (stays in flight)
      __builtin_amdgcn_s_barrier();          // phase-align the 8 waves (no drain)
      asm volatile("s_waitcnt lgkmcnt(0)" ::: "memory");
      __builtin_amdgcn_sched_barrier(0);     // rule #18: MFMA must not hoist past wait
      if (t < 8) loadB(xb, t + 1, nxtB);     // issue B(t+1); hides under MFMA cluster
      __builtin_amdgcn_s_setprio(1);
#pragma unroll
      for (int nj = 0; nj < 4; ++nj)
#pragma unroll
        for (int mi = 0; mi < 4; ++mi)
          acc[mi][nj] = __builtin_amdgcn_mfma_f32_16x16x32_bf16(curA[mi], curB[nj], acc[mi][nj], 0, 0, 0);
      __builtin_amdgcn_s_setprio(0);
    }
    if (c < 7) {
      // counted drain: stageX(c+1) done; 8 newest vmem (A prefetches) in flight.
      asm volatile("s_waitcnt vmcnt(8) lgkmcnt(0)" ::: "memory");
      __builtin_amdgcn_s_barrier();
      asm volatile("" ::: "memory");
    }
  }
  __syncthreads();                  // full drain before smem reuse

  // ---- K-split reduction (kp1 -> LDS -> kp0) ----
#pragma unroll
  for (int p = 0; p < 2; ++p) {
    if (kp == 1 && wr == p) {
#pragma unroll
      for (int mi = 0; mi < 4; ++mi)
#pragma unroll
        for (int nj = 0; nj < 4; ++nj)
          *reinterpret_cast<f32x4*>(smem + wc * 16384 + (mi * 4 + nj) * 1024 + lane * 16) = acc[mi][nj];
    }
    __syncthreads();
    if (kp == 0 && wr == p) {
#pragma unroll
      for (int mi = 0; mi < 4; ++mi)
#pragma unroll
        for (int nj = 0; nj < 4; ++nj) {
          f32x4 v = *reinterpret_cast<const f32x4*>(smem + wc * 16384 + (mi * 4 + nj) * 1024 + lane * 16);
          acc[mi][nj] = acc[mi][nj] + v;
        }
    }
    __syncthreads();
  }

  // ---- epilogue: demod + bias, fp32 NCHW store ----
  if (kp == 0) {
    const float* rcpb = rcp + b * 512;
#pragma unroll
    for (int mi = 0; mi < 4; ++mi) {
      int ob = cog * 128 + wr * 64 + mi * 16 + l4 * 4;
      float rc[4], bi[4];
#pragma unroll
      for (int jj = 0; jj < 4; ++jj) { rc[jj] = rcpb[ob + jj]; bi[jj] = bias[ob + jj]; }
#pragma unroll
      for (int nj = 0; nj < 4; ++nj) {
        int row4 = wc * 2 + (nj >> 1);
        int wcol = (nj & 1) * 16 + l15;
        int h = hg * 4 + row4;
#pragma unroll
        for (int jj = 0; jj < 4; ++jj)
          out[(((size_t)b * 512 + ob + jj) * 32 + h) * 32 + wcol] = acc[mi][nj][jj] * rc[jj] + bi[jj];
      }
    }
  }
}

extern "C" void kernel_launch(void* const* d_in, const int* in_sizes, int n_in,
                              void* d_out, int out_size, void* d_ws, size_t ws_size,
                              hipStream_t stream) {
  const float* x    = (const float*)d_in[0];
  const float* ys   = (const float*)d_in[1];
  const float* w    = (const float*)d_in[2];
  const float* bias = (const float*)d_in[3];
  float* out = (float*)d_out;
  char* ws = (char*)d_ws;
  float* rcp = (float*)(ws + RCP_OFF);
  unsigned short* wpre = (unsigned short*)(ws + WPRE_OFF);
  unsigned short* xm   = (unsigned short*)(ws + XM_OFF);

  prep_kernel<<<768, 256, 0, stream>>>(x, ys, w, xm, wpre, rcp);
  conv_main<<<256, 512, 0, stream>>>(wpre, xm, rcp, bias, out);
}